// Round 2
// baseline (291.989 us; speedup 1.0000x reference)
//
#include <hip/hip_runtime.h>
#include <hip/hip_bf16.h>
#include <stdint.h>

typedef __bf16 bf16;
typedef __attribute__((ext_vector_type(8))) __bf16 bf16x8;
typedef __attribute__((ext_vector_type(4))) __bf16 bf16x4;
typedef __attribute__((ext_vector_type(4))) float f32x4;

#define AS1 __attribute__((address_space(1)))
#define AS3 __attribute__((address_space(3)))

__device__ __forceinline__ void gl_lds16(const void* g, void* l) {
  __builtin_amdgcn_global_load_lds((const AS1 uint32_t*)g, (AS3 uint32_t*)l, 16, 0, 0);
}

#define FENCE() asm volatile("" ::: "memory")
#define BAR()                        \
  do {                               \
    FENCE();                         \
    __builtin_amdgcn_s_barrier();    \
    FENCE();                         \
  } while (0)
// rule #18: sched_barrier(0) right after an inline-asm lgkmcnt so MFMA can't hoist
#define LGKM0()                                   \
  do {                                            \
    asm volatile("s_waitcnt lgkmcnt(0)" ::: "memory"); \
    __builtin_amdgcn_sched_barrier(0);            \
  } while (0)
#define VMW6() asm volatile("s_waitcnt vmcnt(6)" ::: "memory")
#define VMW0() asm volatile("s_waitcnt vmcnt(0)" ::: "memory")

// ---------------- 256x256 8-phase pipelined GEMM: C = A * B^T ----------------
// m201-faithful schedule. A [M,K] bf16 row-major, B [N,K] bf16 row-major.
// BK=64, 512 thr = 8 waves (2M x 4N), per-wave 128x64 output, 2x64KB LDS dbuf.
// Per phase: {ds_read subtile | stage 1 half-tile (2 gl_lds) | BAR | lgkm0 |
// setprio1 | 16 MFMA | setprio0 | BAR}. Counted vmcnt(6) once per K-tile
// (3 half-tiles in flight, issued 4-7 phases before their wait -> HBM latency
// covered). Staging ~1.75 tiles ahead:
//   P0(t): AH1(t+1) -> other buf (idle since tile t-1)
//   P1(t): AH0(t+2) -> cur buf (AH0 last read P0)
//   P2(t): BH0(t+2) -> cur buf (BH0 last read P0; held in regs after)
//   P3(t): BH1(t+2) -> cur buf (BH1 last read P1)
// End-of-tile vmcnt(6) retires everything except the newest 3 halves ->
// tile t+1 fully landed before its phase 0.
// MODE 1: C = exp(alpha*AB^T), lsum[z*2048+row] += row-sum (atomics)
// MODE 2: C = alpha*AB^T / lsum[z*2048+row]
// MODE 4: QKV split-store: n0<1024 -> Cbase(Q), <2048 -> C2(K), else C3(V)
template <int MODE>
__global__ __launch_bounds__(512, 2) void gemm256(
    const bf16* __restrict__ Abase, const bf16* __restrict__ Bbase,
    bf16* __restrict__ Cbase, int K, int lda, int ldb, int ldc,
    long long sA, long long sB, long long sC, float alpha,
    float* __restrict__ lsum, bf16* __restrict__ C2, bf16* __restrict__ C3) {
  extern __shared__ char smem[];  // 128 KB: 2 x (A 32KB | B 32KB)
  const int z = blockIdx.z;
  const bf16* A = Abase + (long long)z * sA;
  const bf16* B = Bbase + (long long)z * sB;
  bf16* C = Cbase + (long long)z * sC;
  const int m0 = blockIdx.y * 256, n0 = blockIdx.x * 256;
  const int t = threadIdx.x;
  const int lane = t & 63;
  const int wid = t >> 6, wrow = wid >> 2, wcol = wid & 3;
  const int quad = lane >> 4, r = lane & 15;

  // staging: thread writes 16B; global source k-chunk pre-XOR-swizzled so the
  // LDS destination stays linear (gl_lds wave-uniform-dest constraint)
  const int rowq = t >> 3;
  const int chunk = (t & 7) ^ (rowq & 7);
  const bf16* pA0 = A + (long long)(m0 + rowq) * lda + chunk * 8;
  const bf16* pB0 = B + (long long)(n0 + rowq) * ldb + chunk * 8;

  // reader offsets (verified R1: conflict-free, correct results)
  const int aoff = (wrow * 64 + r) * 128;
  const int boff = 32768 + (wcol * 32 + r) * 128;
  const int cs0 = ((quad) ^ (r & 7)) * 16;      // kk=0 chunk
  const int cs1 = ((4 + quad) ^ (r & 7)) * 16;  // kk=1 chunk

#define STAGE_A(HALF, KT, SB)                                                  \
  do {                                                                         \
    gl_lds16(pA0 + (long long)((HALF) * 128) * lda + (KT),                     \
             (SB) + (HALF) * 16384 + t * 16);                                  \
    gl_lds16(pA0 + (long long)((HALF) * 128 + 64) * lda + (KT),                \
             (SB) + (HALF) * 16384 + 8192 + t * 16);                           \
  } while (0)
#define STAGE_B(HALF, KT, SB)                                                  \
  do {                                                                         \
    gl_lds16(pB0 + (long long)((HALF) * 128) * ldb + (KT),                     \
             (SB) + 32768 + (HALF) * 16384 + t * 16);                          \
    gl_lds16(pB0 + (long long)((HALF) * 128 + 64) * ldb + (KT),                \
             (SB) + 32768 + (HALF) * 16384 + 8192 + t * 16);                   \
  } while (0)
#define READ_A(MH)                                                             \
  _Pragma("unroll") for (int mr = 0; mr < 4; ++mr) {                           \
    af[mr][0] = *(const bf16x8*)(Sc + (MH) * 16384 + aoff + mr * 2048 + cs0);  \
    af[mr][1] = *(const bf16x8*)(Sc + (MH) * 16384 + aoff + mr * 2048 + cs1);  \
  }
#define READ_B(NH)                                                             \
  _Pragma("unroll") for (int nr = 0; nr < 2; ++nr) {                           \
    bfr[NH][nr][0] =                                                           \
        *(const bf16x8*)(Sc + (NH) * 16384 + boff + nr * 2048 + cs0);          \
    bfr[NH][nr][1] =                                                           \
        *(const bf16x8*)(Sc + (NH) * 16384 + boff + nr * 2048 + cs1);          \
  }
#define MMA(MH, NH)                                                            \
  _Pragma("unroll") for (int mr = 0; mr < 4; ++mr)                             \
      _Pragma("unroll") for (int nr = 0; nr < 2; ++nr) {                       \
    acc[MH][NH][mr][nr] = __builtin_amdgcn_mfma_f32_16x16x32_bf16(             \
        af[mr][0], bfr[NH][nr][0], acc[MH][NH][mr][nr], 0, 0, 0);              \
    acc[MH][NH][mr][nr] = __builtin_amdgcn_mfma_f32_16x16x32_bf16(             \
        af[mr][1], bfr[NH][nr][1], acc[MH][NH][mr][nr], 0, 0, 0);              \
  }

  f32x4 acc[2][2][4][2] = {};
  bf16x8 af[4][2];
  bf16x8 bfr[2][2][2];
  char* Sc = smem;
  char* Sn = smem + 65536;
  const int T = K >> 6;

  // prologue: tile0 (4 halves) + tile1's AH0,BH0,BH1. vmcnt(6) => tile0 landed,
  // outstanding 6 = tile1's first 3 halves (steady-state carry).
  STAGE_A(0, 0, Sc);
  STAGE_B(0, 0, Sc);
  STAGE_A(1, 0, Sc);
  STAGE_B(1, 0, Sc);
  {
    const int kt1p = (T > 1) ? 64 : 0;
    STAGE_A(0, kt1p, Sn);
    STAGE_B(0, kt1p, Sn);
    STAGE_B(1, kt1p, Sn);
  }
  VMW6();
  BAR();

  for (int tt = 0; tt < T; ++tt) {
    const int kt1 = (tt + 1 < T ? tt + 1 : 0) << 6;
    const int kt2 = (tt + 2 < T ? tt + 2 : 0) << 6;
    // P0: quadrant (0,0); read AH0+BH0 (12 ds_read); stage AH1(t+1)->Sn
    READ_A(0);
    READ_B(0);
    STAGE_A(1, kt1, Sn);
    BAR();
    LGKM0();
    __builtin_amdgcn_s_setprio(1);
    MMA(0, 0);
    __builtin_amdgcn_s_setprio(0);
    BAR();
    // P1: (0,1); read BH1 (4); stage AH0(t+2) over dead region of cur buf
    READ_B(1);
    STAGE_A(0, kt2, Sc);
    BAR();
    LGKM0();
    __builtin_amdgcn_s_setprio(1);
    MMA(0, 1);
    __builtin_amdgcn_s_setprio(0);
    BAR();
    // P2: (1,0); read AH1 (8); stage BH0(t+2)
    READ_A(1);
    STAGE_B(0, kt2, Sc);
    BAR();
    LGKM0();
    __builtin_amdgcn_s_setprio(1);
    MMA(1, 0);
    __builtin_amdgcn_s_setprio(0);
    BAR();
    // P3: (1,1); no reads; stage BH1(t+2); counted vmcnt: tile t+1 landed
    STAGE_B(1, kt2, Sc);
    BAR();
    __builtin_amdgcn_s_setprio(1);
    MMA(1, 1);
    __builtin_amdgcn_s_setprio(0);
    VMW6();
    BAR();
    char* tp = Sc;
    Sc = Sn;
    Sn = tp;
  }
  VMW0();  // drain outstanding (dummy) LDS-DMA before waves exit

  // C/D layout: col = lane&15, row = quad*4 + reg  [verified m89/m91]
  if constexpr (MODE == 4) {
    bf16* dst;
    int c0;
    if (n0 < 1024) {
      dst = Cbase;
      c0 = n0;
    } else if (n0 < 2048) {
      dst = C2;
      c0 = n0 - 1024;
    } else {
      dst = C3;
      c0 = n0 - 2048;
    }
#pragma unroll
    for (int mh = 0; mh < 2; ++mh)
#pragma unroll
      for (int mr = 0; mr < 4; ++mr) {
        const int row0 = m0 + mh * 128 + wrow * 64 + mr * 16 + quad * 4;
#pragma unroll
        for (int nh = 0; nh < 2; ++nh)
#pragma unroll
          for (int nr = 0; nr < 2; ++nr) {
            const int col = c0 + nh * 128 + wcol * 32 + nr * 16 + r;
#pragma unroll
            for (int rg = 0; rg < 4; ++rg)
              dst[(long long)(row0 + rg) * 1024 + col] =
                  (bf16)acc[mh][nh][mr][nr][rg];
          }
      }
    return;
  }

#pragma unroll
  for (int mh = 0; mh < 2; ++mh)
#pragma unroll
    for (int mr = 0; mr < 4; ++mr) {
      const int row0 = m0 + mh * 128 + wrow * 64 + mr * 16 + quad * 4;
      float rsum[4] = {0.f, 0.f, 0.f, 0.f};
      float inv[4];
      if constexpr (MODE == 2) {
#pragma unroll
        for (int rg = 0; rg < 4; ++rg)
          inv[rg] = 1.f / lsum[(long long)z * 2048 + row0 + rg];
      }
#pragma unroll
      for (int nh = 0; nh < 2; ++nh)
#pragma unroll
        for (int nr = 0; nr < 2; ++nr) {
          const int col = n0 + nh * 128 + wcol * 32 + nr * 16 + r;
#pragma unroll
          for (int rg = 0; rg < 4; ++rg) {
            float v = acc[mh][nh][mr][nr][rg] * alpha;
            if constexpr (MODE == 1) {
              // scores/32 ~ N(0,1): fp32 exp needs no max-shift
              bf16 eb = (bf16)__expf(v);
              C[(long long)(row0 + rg) * ldc + col] = eb;
              rsum[rg] += (float)eb;  // sum the rounded numerator
            } else if constexpr (MODE == 2) {
              C[(long long)(row0 + rg) * ldc + col] = (bf16)(v * inv[rg]);
            } else {
              C[(long long)(row0 + rg) * ldc + col] = (bf16)v;
            }
          }
        }
      if constexpr (MODE == 1) {
#pragma unroll
        for (int rg = 0; rg < 4; ++rg) {
#pragma unroll
          for (int off = 8; off >= 1; off >>= 1)
            rsum[rg] += __shfl_xor(rsum[rg], off);
          if (r == 0)
            atomicAdd(&lsum[(long long)z * 2048 + row0 + rg], rsum[rg]);
        }
      }
    }
#undef STAGE_A
#undef STAGE_B
#undef READ_A
#undef READ_B
#undef MMA
}

// ---------------- 128x128 tile GEMM (kept for the small Wo@V^T) ----------
template <int MODE>
__global__ __launch_bounds__(256) void gemm128(
    const bf16* __restrict__ Abase, const bf16* __restrict__ Bbase,
    bf16* __restrict__ Cbase, int K, int lda, int ldb, int ldc,
    long long sA, long long sB, long long sC, float alpha,
    float* __restrict__ lsum, bf16* __restrict__ C2, bf16* __restrict__ C3) {
  extern __shared__ char smem[];  // 32 KB staging
  const int z = blockIdx.z;
  const bf16* A = Abase + (long long)z * sA;
  const bf16* B = Bbase + (long long)z * sB;
  bf16* C = Cbase + (long long)z * sC;
  const int m0 = blockIdx.y * 128, n0 = blockIdx.x * 128;
  const int t = threadIdx.x;
  const int lane = t & 63, wave = t >> 6;
  const int wm = (wave >> 1) * 64, wn = (wave & 1) * 64;
  const int quad = lane >> 4, r = lane & 15;

  const int srow = t >> 3;
  const int schunk = (t & 7) ^ (srow & 7);
  const bf16* ga = A + (long long)(m0 + srow) * lda + schunk * 8;
  const bf16* gb = B + (long long)(n0 + srow) * ldb + schunk * 8;
  char* la = smem + t * 16;
  char* lb = smem + 16384 + t * 16;

  f32x4 acc[4][4] = {};

  for (int k0 = 0; k0 < K; k0 += 64) {
    __syncthreads();
#pragma unroll
    for (int rd = 0; rd < 4; rd++) {
      gl_lds16(ga + (long long)(32 * rd) * lda, la + rd * 4096);
      gl_lds16(gb + (long long)(32 * rd) * ldb, lb + rd * 4096);
    }
    ga += 64;
    gb += 64;
    __syncthreads();

#pragma unroll
    for (int kk = 0; kk < 2; kk++) {
      bf16x8 af[4], bfr[4];
      const int csa = ((kk * 4 + quad) ^ (r & 7)) * 16;
      const char* pa = smem + (wm + r) * 128 + csa;
      const char* pb = smem + 16384 + (wn + r) * 128 + csa;
#pragma unroll
      for (int i = 0; i < 4; i++) af[i] = *(const bf16x8*)(pa + i * 2048);
#pragma unroll
      for (int j = 0; j < 4; j++) bfr[j] = *(const bf16x8*)(pb + j * 2048);
#pragma unroll
      for (int i = 0; i < 4; i++)
#pragma unroll
        for (int j = 0; j < 4; j++)
          acc[i][j] = __builtin_amdgcn_mfma_f32_16x16x32_bf16(af[i], bfr[j],
                                                              acc[i][j], 0, 0, 0);
    }
  }

#pragma unroll
  for (int i = 0; i < 4; i++) {
    const int row0 = m0 + wm + i * 16 + quad * 4;
#pragma unroll
    for (int j = 0; j < 4; j++) {
      const int col = n0 + wn + j * 16 + r;
#pragma unroll
      for (int rg = 0; rg < 4; rg++) {
        float v = acc[i][j][rg] * alpha;
        C[(long long)(row0 + rg) * ldc + col] = (bf16)v;
      }
    }
  }
}

// ---------------- prep: x->bf16 convert + 4 weight transposes + lsum zero ----
__global__ __launch_bounds__(256) void prep(
    const float* __restrict__ x, const float* __restrict__ Wq,
    const float* __restrict__ Wk, const float* __restrict__ Wv,
    const float* __restrict__ Wo, bf16* __restrict__ Xb,
    bf16* __restrict__ Wcat, bf16* __restrict__ Wot,
    float* __restrict__ lsum) {
  __shared__ float tile[32][33];
  const int bx = blockIdx.x;
  const int t = threadIdx.x;
  if (bx < 4096) {
    if (bx < 32) lsum[bx * 256 + t] = 0.f;
    long long i = (long long)bx * 256 + t;
    const float4* p = (const float4*)x;
    float4 a = p[i * 2], b = p[i * 2 + 1];
    bf16x8 o;
    o[0] = (bf16)a.x; o[1] = (bf16)a.y; o[2] = (bf16)a.z; o[3] = (bf16)a.w;
    o[4] = (bf16)b.x; o[5] = (bf16)b.y; o[6] = (bf16)b.z; o[7] = (bf16)b.w;
    ((bf16x8*)Xb)[i] = o;
  } else {
    int idx = bx - 4096;
    const int zw = idx >> 10;
    idx &= 1023;
    const int tiy = idx >> 5, tix = idx & 31;
    const float* W = (zw == 0) ? Wq : (zw == 1) ? Wk : (zw == 2) ? Wv : Wo;
    bf16* dst = (zw < 3) ? (Wcat + (long long)zw * 1024 * 1024) : Wot;
    const int bx0 = tix * 32, by0 = tiy * 32;
    const int ttx = t & 31, tty = t >> 5;
#pragma unroll
    for (int i = 0; i < 32; i += 8)
      tile[tty + i][ttx] = W[(long long)(by0 + tty + i) * 1024 + bx0 + ttx];
    __syncthreads();
#pragma unroll
    for (int i = 0; i < 32; i += 8)
      dst[(long long)(bx0 + tty + i) * 1024 + by0 + ttx] = (bf16)tile[ttx][tty + i];
  }
}

// one block per row of 1024 (bf16 hidden in, fp32 out)
__global__ __launch_bounds__(256) void layernorm_rows(
    const bf16* __restrict__ H, const float* __restrict__ gamma,
    const float* __restrict__ beta, float* __restrict__ O) {
  const long long row = blockIdx.x;
  const bf16* h = H + row * 1024;
  float* o = O + row * 1024;
  const int t = threadIdx.x;
  const int lane = t & 63, wave = t >> 6;
  bf16x4 hv = ((const bf16x4*)h)[t];
  float v[4] = {(float)hv[0], (float)hv[1], (float)hv[2], (float)hv[3]};
  float s = v[0] + v[1] + v[2] + v[3];
  float ss = v[0] * v[0] + v[1] * v[1] + v[2] * v[2] + v[3] * v[3];
#pragma unroll
  for (int off = 32; off >= 1; off >>= 1) {
    s += __shfl_xor(s, off);
    ss += __shfl_xor(ss, off);
  }
  __shared__ float rs[4], rss[4];
  if (lane == 0) {
    rs[wave] = s;
    rss[wave] = ss;
  }
  __syncthreads();
  s = rs[0] + rs[1] + rs[2] + rs[3];
  ss = rss[0] + rss[1] + rss[2] + rss[3];
  const float mean = s * (1.f / 1024.f);
  const float var = ss * (1.f / 1024.f) - mean * mean;
  const float rstd = rsqrtf(var + 1e-5f);
  float4 g = ((const float4*)gamma)[t];
  float4 bb = ((const float4*)beta)[t];
  float4 rr;
  rr.x = (v[0] - mean) * rstd * g.x + bb.x;
  rr.y = (v[1] - mean) * rstd * g.y + bb.y;
  rr.z = (v[2] - mean) * rstd * g.z + bb.z;
  rr.w = (v[3] - mean) * rstd * g.w + bb.w;
  ((float4*)o)[t] = rr;
}

extern "C" void kernel_launch(void* const* d_in, const int* in_sizes, int n_in,
                              void* d_out, int out_size, void* d_ws,
                              size_t ws_size, hipStream_t stream) {
  const float* x = (const float*)d_in[0];
  const float* Wq = (const float*)d_in[1];
  const float* Wk = (const float*)d_in[2];
  const float* Wv = (const float*)d_in[3];
  const float* Wo = (const float*)d_in[4];
  const float* gamma = (const float*)d_in[5];
  const float* beta = (const float*)d_in[6];
  float* out = (float*)d_out;

  char* ws = (char*)d_ws;
  const size_t MB = 1024ull * 1024ull;
  bf16* Xb = (bf16*)(ws + 0);             // 16 MB [8192,1024]
  bf16* Wcat = (bf16*)(ws + 16 * MB);     // 6 MB  [3072,1024]
  bf16* Wot = (bf16*)(ws + 22 * MB);      // 2 MB  [1024,1024]
  bf16* Qd = (bf16*)(ws + 24 * MB);       // 16 MB [8192,1024]
  bf16* Kd = (bf16*)(ws + 40 * MB);       // 16 MB [8192,1024]
  bf16* Vd = (bf16*)(ws + 56 * MB);       // 16 MB [8192,1024]
  bf16* expS = (bf16*)(ws + 72 * MB);     // 32 MB [4][2048,2048]
  float* lsum = (float*)(ws + 104 * MB);  // 32 KB [4][2048]
  bf16* VWo = (bf16*)(ws + 105 * MB);     // 16 MB [4][1024,2048] (d, s)
  bf16* Hd = (bf16*)(ws + 121 * MB);      // 16 MB [8192,1024]

  static int inited = 0;
  if (!inited) {
    hipFuncSetAttribute(reinterpret_cast<const void*>(&gemm256<4>),
                        hipFuncAttributeMaxDynamicSharedMemorySize, 131072);
    hipFuncSetAttribute(reinterpret_cast<const void*>(&gemm256<1>),
                        hipFuncAttributeMaxDynamicSharedMemorySize, 131072);
    hipFuncSetAttribute(reinterpret_cast<const void*>(&gemm256<2>),
                        hipFuncAttributeMaxDynamicSharedMemorySize, 131072);
    inited = 1;
  }

  prep<<<8192, 256, 0, stream>>>(x, Wq, Wk, Wv, Wo, Xb, Wcat, Wot, lsum);

  // Q/K/V = Xb @ Wcat^T (M=8192,N=3072,K=1024), split-stored dense
  gemm256<4><<<dim3(12, 32, 1), 512, 131072, stream>>>(
      Xb, Wcat, Qd, 1024, 1024, 1024, 1024, 0, 0, 0, 1.f, nullptr, Kd, Vd);

  // expS = exp(Q @ K^T / 32), lsum = row sums (M=N=2048,K=1024, x4)
  gemm256<1><<<dim3(8, 8, 4), 512, 131072, stream>>>(
      Qd, Kd, expS, 1024, 1024, 1024, 2048, 2048 * 1024LL, 2048 * 1024LL,
      2048 * 2048LL, 0.03125f, lsum, nullptr, nullptr);

  // VWo[d][s] = Wot @ V^T  (A=Wot [1024,1024], B=V [2048,1024], x4)
  gemm128<0><<<dim3(16, 8, 4), 256, 32768, stream>>>(
      Wot, Vd, VWo, 1024, 1024, 1024, 2048, 0, 2048 * 1024LL, 1024 * 2048LL,
      1.f, nullptr, nullptr, nullptr);

  // hidden = (expS @ VWo^T) / lsum  (M=2048,N=1024,K=2048, x4)
  gemm256<2><<<dim3(4, 8, 4), 512, 131072, stream>>>(
      expS, VWo, Hd, 2048, 2048, 2048, 1024, 2048 * 2048LL, 1024 * 2048LL,
      2048 * 1024LL, 1.f, lsum, nullptr, nullptr);

  layernorm_rows<<<8192, 256, 0, stream>>>(Hd, gamma, beta, out);
}

// Round 3
// 262.860 us; speedup vs baseline: 1.1108x; 1.1108x over previous
//
#include <hip/hip_runtime.h>
#include <hip/hip_bf16.h>
#include <stdint.h>

typedef __bf16 bf16;
typedef __attribute__((ext_vector_type(8))) __bf16 bf16x8;
typedef __attribute__((ext_vector_type(4))) __bf16 bf16x4;
typedef __attribute__((ext_vector_type(4))) float f32x4;

#define AS1 __attribute__((address_space(1)))
#define AS3 __attribute__((address_space(3)))

__device__ __forceinline__ void gl_lds16(const void* g, void* l) {
  __builtin_amdgcn_global_load_lds((const AS1 uint32_t*)g, (AS3 uint32_t*)l, 16, 0, 0);
}

#define FENCE() asm volatile("" ::: "memory")
#define BAR()                        \
  do {                               \
    FENCE();                         \
    __builtin_amdgcn_s_barrier();    \
    FENCE();                         \
  } while (0)
#define VMW4() asm volatile("s_waitcnt vmcnt(4)" ::: "memory")

// ---------------- 256x256 pipelined GEMM (R1 variant) ----------------
// Used ONLY for expS (grid 8x8x4 = 256 blocks = exactly 1 round at 1 blk/CU).
// Single barrier per phase + counted vmcnt(4) per K-tile (R1 measured best of
// the 256-tile variants at these shapes).
template <int MODE>
__global__ __launch_bounds__(512, 2) void gemm256(
    const bf16* __restrict__ Abase, const bf16* __restrict__ Bbase,
    bf16* __restrict__ Cbase, int K, int lda, int ldb, int ldc,
    long long sA, long long sB, long long sC, float alpha,
    float* __restrict__ lsum, bf16* __restrict__ C2, bf16* __restrict__ C3) {
  extern __shared__ char smem[];  // 128 KB: 2 x (A 32KB | B 32KB)
  const int z = blockIdx.z;
  const bf16* A = Abase + (long long)z * sA;
  const bf16* B = Bbase + (long long)z * sB;
  bf16* C = Cbase + (long long)z * sC;
  const int m0 = blockIdx.y * 256, n0 = blockIdx.x * 256;
  const int t = threadIdx.x;
  const int lane = t & 63;
  const int wid = t >> 6, wrow = wid >> 2, wcol = wid & 3;
  const int quad = lane >> 4, r = lane & 15;

  const int rowq = t >> 3;
  const int chunk = (t & 7) ^ (rowq & 7);
  const bf16* pA0 = A + (long long)(m0 + rowq) * lda + chunk * 8;
  const bf16* pB0 = B + (long long)(n0 + rowq) * ldb + chunk * 8;

  const int aoff = (wrow * 64 + r) * 128;
  const int boff = 32768 + (wcol * 32 + r) * 128;
  const int cs0 = ((quad) ^ (r & 7)) * 16;      // kk=0 chunk
  const int cs1 = ((4 + quad) ^ (r & 7)) * 16;  // kk=1 chunk

#define STAGE_A(HALF, KT, SB)                                                  \
  do {                                                                         \
    gl_lds16(pA0 + (long long)((HALF) * 128) * lda + (KT),                     \
             (SB) + (HALF) * 16384 + t * 16);                                  \
    gl_lds16(pA0 + (long long)((HALF) * 128 + 64) * lda + (KT),                \
             (SB) + (HALF) * 16384 + 8192 + t * 16);                           \
  } while (0)
#define STAGE_B(HALF, KT, SB)                                                  \
  do {                                                                         \
    gl_lds16(pB0 + (long long)((HALF) * 128) * ldb + (KT),                     \
             (SB) + 32768 + (HALF) * 16384 + t * 16);                          \
    gl_lds16(pB0 + (long long)((HALF) * 128 + 64) * ldb + (KT),                \
             (SB) + 32768 + (HALF) * 16384 + 8192 + t * 16);                   \
  } while (0)
#define READ_A(MH)                                                             \
  _Pragma("unroll") for (int mr = 0; mr < 4; ++mr) {                           \
    af[mr][0] = *(const bf16x8*)(Sc + (MH) * 16384 + aoff + mr * 2048 + cs0);  \
    af[mr][1] = *(const bf16x8*)(Sc + (MH) * 16384 + aoff + mr * 2048 + cs1);  \
  }
#define READ_B(NH)                                                             \
  _Pragma("unroll") for (int nr = 0; nr < 2; ++nr) {                           \
    bfr[NH][nr][0] =                                                           \
        *(const bf16x8*)(Sc + (NH) * 16384 + boff + nr * 2048 + cs0);          \
    bfr[NH][nr][1] =                                                           \
        *(const bf16x8*)(Sc + (NH) * 16384 + boff + nr * 2048 + cs1);          \
  }
#define MMA(MH, NH)                                                            \
  _Pragma("unroll") for (int mr = 0; mr < 4; ++mr)                             \
      _Pragma("unroll") for (int nr = 0; nr < 2; ++nr) {                       \
    acc[MH][NH][mr][nr] = __builtin_amdgcn_mfma_f32_16x16x32_bf16(             \
        af[mr][0], bfr[NH][nr][0], acc[MH][NH][mr][nr], 0, 0, 0);              \
    acc[MH][NH][mr][nr] = __builtin_amdgcn_mfma_f32_16x16x32_bf16(             \
        af[mr][1], bfr[NH][nr][1], acc[MH][NH][mr][nr], 0, 0, 0);              \
  }

  f32x4 acc[2][2][4][2] = {};
  bf16x8 af[4][2];
  bf16x8 bfr[2][2][2];
  char* Sc = smem;
  char* Sn = smem + 65536;
  const int T = K >> 6;

  // prologue: tile0 fully + tile1 H0 halves; vmcnt(4) => tile0 landed
  STAGE_A(0, 0, Sc);
  STAGE_B(0, 0, Sc);
  STAGE_A(1, 0, Sc);
  STAGE_B(1, 0, Sc);
  {
    const int kt1p = (T > 1) ? 64 : 0;
    STAGE_A(0, kt1p, Sn);
    STAGE_B(0, kt1p, Sn);
  }
  VMW4();
  BAR();

  for (int tt = 0; tt < T; ++tt) {
    const int kt1 = (tt + 1 < T ? tt + 1 : 0) << 6;
    const int kt2 = (tt + 2 < T ? tt + 2 : 0) << 6;
    // phase 0: quadrant (0,0); prefetch A-H1(t+1) into idle buf
    READ_A(0);
    READ_B(0);
    STAGE_A(1, kt1, Sn);
    __builtin_amdgcn_s_setprio(1);
    MMA(0, 0);
    __builtin_amdgcn_s_setprio(0);
    BAR();
    // phase 1: (0,1); prefetch B-H1(t+1)
    READ_B(1);
    STAGE_B(1, kt1, Sn);
    __builtin_amdgcn_s_setprio(1);
    MMA(0, 1);
    __builtin_amdgcn_s_setprio(0);
    BAR();
    // phase 2: (1,0); restage A-H0(t+2) over dead region of current buf
    READ_A(1);
    STAGE_A(0, kt2, Sc);
    __builtin_amdgcn_s_setprio(1);
    MMA(1, 0);
    __builtin_amdgcn_s_setprio(0);
    BAR();
    // phase 3: (1,1); restage B-H0(t+2); counted wait: tile t+1 landed
    STAGE_B(0, kt2, Sc);
    __builtin_amdgcn_s_setprio(1);
    MMA(1, 1);
    __builtin_amdgcn_s_setprio(0);
    VMW4();
    BAR();
    char* tp = Sc;
    Sc = Sn;
    Sn = tp;
  }

  // C/D layout: col = lane&15, row = quad*4 + reg  [verified m89/m91]
  if constexpr (MODE == 4) {
    bf16* dst;
    int c0;
    if (n0 < 1024) {
      dst = Cbase;
      c0 = n0;
    } else if (n0 < 2048) {
      dst = C2;
      c0 = n0 - 1024;
    } else {
      dst = C3;
      c0 = n0 - 2048;
    }
#pragma unroll
    for (int mh = 0; mh < 2; ++mh)
#pragma unroll
      for (int mr = 0; mr < 4; ++mr) {
        const int row0 = m0 + mh * 128 + wrow * 64 + mr * 16 + quad * 4;
#pragma unroll
        for (int nh = 0; nh < 2; ++nh)
#pragma unroll
          for (int nr = 0; nr < 2; ++nr) {
            const int col = c0 + nh * 128 + wcol * 32 + nr * 16 + r;
#pragma unroll
            for (int rg = 0; rg < 4; ++rg)
              dst[(long long)(row0 + rg) * 1024 + col] =
                  (bf16)acc[mh][nh][mr][nr][rg];
          }
      }
    return;
  }

#pragma unroll
  for (int mh = 0; mh < 2; ++mh)
#pragma unroll
    for (int mr = 0; mr < 4; ++mr) {
      const int row0 = m0 + mh * 128 + wrow * 64 + mr * 16 + quad * 4;
      float rsum[4] = {0.f, 0.f, 0.f, 0.f};
      float inv[4];
      if constexpr (MODE == 2) {
#pragma unroll
        for (int rg = 0; rg < 4; ++rg)
          inv[rg] = 1.f / lsum[(long long)z * 2048 + row0 + rg];
      }
#pragma unroll
      for (int nh = 0; nh < 2; ++nh)
#pragma unroll
        for (int nr = 0; nr < 2; ++nr) {
          const int col = n0 + nh * 128 + wcol * 32 + nr * 16 + r;
#pragma unroll
          for (int rg = 0; rg < 4; ++rg) {
            float v = acc[mh][nh][mr][nr][rg] * alpha;
            if constexpr (MODE == 1) {
              // scores/32 ~ N(0,1): fp32 exp needs no max-shift
              bf16 eb = (bf16)__expf(v);
              C[(long long)(row0 + rg) * ldc + col] = eb;
              rsum[rg] += (float)eb;  // sum the rounded numerator
            } else if constexpr (MODE == 2) {
              C[(long long)(row0 + rg) * ldc + col] = (bf16)(v * inv[rg]);
            } else {
              C[(long long)(row0 + rg) * ldc + col] = (bf16)v;
            }
          }
        }
      if constexpr (MODE == 1) {
#pragma unroll
        for (int rg = 0; rg < 4; ++rg) {
#pragma unroll
          for (int off = 8; off >= 1; off >>= 1)
            rsum[rg] += __shfl_xor(rsum[rg], off);
          if (r == 0)
            atomicAdd(&lsum[(long long)z * 2048 + row0 + rg], rsum[rg]);
        }
      }
    }
#undef STAGE_A
#undef STAGE_B
#undef READ_A
#undef READ_B
#undef MMA
}

// ---------------- 128x128 tile GEMM: C = A * B^T ----------------
// R0 structure (proven 796 TF, perfect grid fills) + __launch_bounds__(256,3)
// to lift residency 2 -> 3 blocks/CU (regs ~140 of 512/3=170 cap; LDS 3x32KB).
// MODE 0: C = alpha*AB^T
// MODE 1: C = exp(alpha*AB^T), lsum[z*2048+row] += row-sum (atomics)
// MODE 2: C = alpha*AB^T / lsum[z*2048+row]
// MODE 4: QKV split-store: n0<1024 -> Cbase(Q), <2048 -> C2(K), else C3(V)
template <int MODE>
__global__ __launch_bounds__(256, 3) void gemm128(
    const bf16* __restrict__ Abase, const bf16* __restrict__ Bbase,
    bf16* __restrict__ Cbase, int K, int lda, int ldb, int ldc,
    long long sA, long long sB, long long sC, float alpha,
    float* __restrict__ lsum, bf16* __restrict__ C2, bf16* __restrict__ C3) {
  extern __shared__ char smem[];  // 32 KB staging
  const int z = blockIdx.z;
  const bf16* A = Abase + (long long)z * sA;
  const bf16* B = Bbase + (long long)z * sB;
  bf16* C = Cbase + (long long)z * sC;
  const int m0 = blockIdx.y * 128, n0 = blockIdx.x * 128;
  const int t = threadIdx.x;
  const int lane = t & 63, wave = t >> 6;
  const int wm = (wave >> 1) * 64, wn = (wave & 1) * 64;
  const int quad = lane >> 4, r = lane & 15;

  const int srow = t >> 3;
  const int schunk = (t & 7) ^ (srow & 7);
  const bf16* ga = A + (long long)(m0 + srow) * lda + schunk * 8;
  const bf16* gb = B + (long long)(n0 + srow) * ldb + schunk * 8;
  char* la = smem + t * 16;
  char* lb = smem + 16384 + t * 16;

  f32x4 acc[4][4] = {};

  for (int k0 = 0; k0 < K; k0 += 64) {
    __syncthreads();
#pragma unroll
    for (int rd = 0; rd < 4; rd++) {
      gl_lds16(ga + (long long)(32 * rd) * lda, la + rd * 4096);
      gl_lds16(gb + (long long)(32 * rd) * ldb, lb + rd * 4096);
    }
    ga += 64;
    gb += 64;
    __syncthreads();

#pragma unroll
    for (int kk = 0; kk < 2; kk++) {
      bf16x8 af[4], bfr[4];
      const int csa = ((kk * 4 + quad) ^ (r & 7)) * 16;
      const char* pa = smem + (wm + r) * 128 + csa;
      const char* pb = smem + 16384 + (wn + r) * 128 + csa;
#pragma unroll
      for (int i = 0; i < 4; i++) af[i] = *(const bf16x8*)(pa + i * 2048);
#pragma unroll
      for (int j = 0; j < 4; j++) bfr[j] = *(const bf16x8*)(pb + j * 2048);
#pragma unroll
      for (int i = 0; i < 4; i++)
#pragma unroll
        for (int j = 0; j < 4; j++)
          acc[i][j] = __builtin_amdgcn_mfma_f32_16x16x32_bf16(af[i], bfr[j],
                                                              acc[i][j], 0, 0, 0);
    }
  }

  // C/D layout: col = lane&15, row = quad*4 + reg  [verified m89/m91]
  if constexpr (MODE == 4) {
    bf16* dst;
    int c0;
    if (n0 < 1024) {
      dst = Cbase; c0 = n0;
    } else if (n0 < 2048) {
      dst = C2; c0 = n0 - 1024;
    } else {
      dst = C3; c0 = n0 - 2048;
    }
#pragma unroll
    for (int i = 0; i < 4; i++) {
      const int row0 = m0 + wm + i * 16 + quad * 4;
#pragma unroll
      for (int j = 0; j < 4; j++) {
        const int col = c0 + wn + j * 16 + r;
#pragma unroll
        for (int rg = 0; rg < 4; rg++)
          dst[(long long)(row0 + rg) * 1024 + col] = (bf16)acc[i][j][rg];
      }
    }
    return;
  }

#pragma unroll
  for (int i = 0; i < 4; i++) {
    const int row0 = m0 + wm + i * 16 + quad * 4;
    float rsum[4] = {0.f, 0.f, 0.f, 0.f};
    float inv[4];
    if constexpr (MODE == 2) {
#pragma unroll
      for (int rg = 0; rg < 4; rg++)
        inv[rg] = 1.f / lsum[(long long)z * 2048 + row0 + rg];
    }
#pragma unroll
    for (int j = 0; j < 4; j++) {
      const int col = n0 + wn + j * 16 + r;
#pragma unroll
      for (int rg = 0; rg < 4; rg++) {
        float v = acc[i][j][rg] * alpha;
        if constexpr (MODE == 1) {
          // scores/32 ~ N(0,1): fp32 exp needs no max-shift
          bf16 eb = (bf16)__expf(v);
          C[(long long)(row0 + rg) * ldc + col] = eb;
          rsum[rg] += (float)eb;  // sum the rounded numerator
        } else if constexpr (MODE == 2) {
          C[(long long)(row0 + rg) * ldc + col] = (bf16)(v * inv[rg]);
        } else {
          C[(long long)(row0 + rg) * ldc + col] = (bf16)v;
        }
      }
    }
    if constexpr (MODE == 1) {
#pragma unroll
      for (int rg = 0; rg < 4; rg++) {
#pragma unroll
        for (int off = 8; off >= 1; off >>= 1)
          rsum[rg] += __shfl_xor(rsum[rg], off);
        if (r == 0)
          atomicAdd(&lsum[(long long)z * 2048 + row0 + rg], rsum[rg]);
      }
    }
  }
}

// ---------------- prep: x->bf16 convert + 4 weight transposes + lsum zero ----
__global__ __launch_bounds__(256) void prep(
    const float* __restrict__ x, const float* __restrict__ Wq,
    const float* __restrict__ Wk, const float* __restrict__ Wv,
    const float* __restrict__ Wo, bf16* __restrict__ Xb,
    bf16* __restrict__ Wcat, bf16* __restrict__ Wot,
    float* __restrict__ lsum) {
  __shared__ float tile[32][33];
  const int bx = blockIdx.x;
  const int t = threadIdx.x;
  if (bx < 4096) {
    if (bx < 32) lsum[bx * 256 + t] = 0.f;
    long long i = (long long)bx * 256 + t;
    const float4* p = (const float4*)x;
    float4 a = p[i * 2], b = p[i * 2 + 1];
    bf16x8 o;
    o[0] = (bf16)a.x; o[1] = (bf16)a.y; o[2] = (bf16)a.z; o[3] = (bf16)a.w;
    o[4] = (bf16)b.x; o[5] = (bf16)b.y; o[6] = (bf16)b.z; o[7] = (bf16)b.w;
    ((bf16x8*)Xb)[i] = o;
  } else {
    int idx = bx - 4096;
    const int zw = idx >> 10;
    idx &= 1023;
    const int tiy = idx >> 5, tix = idx & 31;
    const float* W = (zw == 0) ? Wq : (zw == 1) ? Wk : (zw == 2) ? Wv : Wo;
    bf16* dst = (zw < 3) ? (Wcat + (long long)zw * 1024 * 1024) : Wot;
    const int bx0 = tix * 32, by0 = tiy * 32;
    const int ttx = t & 31, tty = t >> 5;
#pragma unroll
    for (int i = 0; i < 32; i += 8)
      tile[tty + i][ttx] = W[(long long)(by0 + tty + i) * 1024 + bx0 + ttx];
    __syncthreads();
#pragma unroll
    for (int i = 0; i < 32; i += 8)
      dst[(long long)(bx0 + tty + i) * 1024 + by0 + ttx] = (bf16)tile[ttx][tty + i];
  }
}

// one block per row of 1024 (bf16 hidden in, fp32 out)
__global__ __launch_bounds__(256) void layernorm_rows(
    const bf16* __restrict__ H, const float* __restrict__ gamma,
    const float* __restrict__ beta, float* __restrict__ O) {
  const long long row = blockIdx.x;
  const bf16* h = H + row * 1024;
  float* o = O + row * 1024;
  const int t = threadIdx.x;
  const int lane = t & 63, wave = t >> 6;
  bf16x4 hv = ((const bf16x4*)h)[t];
  float v[4] = {(float)hv[0], (float)hv[1], (float)hv[2], (float)hv[3]};
  float s = v[0] + v[1] + v[2] + v[3];
  float ss = v[0] * v[0] + v[1] * v[1] + v[2] * v[2] + v[3] * v[3];
#pragma unroll
  for (int off = 32; off >= 1; off >>= 1) {
    s += __shfl_xor(s, off);
    ss += __shfl_xor(ss, off);
  }
  __shared__ float rs[4], rss[4];
  if (lane == 0) {
    rs[wave] = s;
    rss[wave] = ss;
  }
  __syncthreads();
  s = rs[0] + rs[1] + rs[2] + rs[3];
  ss = rss[0] + rss[1] + rss[2] + rss[3];
  const float mean = s * (1.f / 1024.f);
  const float var = ss * (1.f / 1024.f) - mean * mean;
  const float rstd = rsqrtf(var + 1e-5f);
  float4 g = ((const float4*)gamma)[t];
  float4 bb = ((const float4*)beta)[t];
  float4 rr;
  rr.x = (v[0] - mean) * rstd * g.x + bb.x;
  rr.y = (v[1] - mean) * rstd * g.y + bb.y;
  rr.z = (v[2] - mean) * rstd * g.z + bb.z;
  rr.w = (v[3] - mean) * rstd * g.w + bb.w;
  ((float4*)o)[t] = rr;
}

extern "C" void kernel_launch(void* const* d_in, const int* in_sizes, int n_in,
                              void* d_out, int out_size, void* d_ws,
                              size_t ws_size, hipStream_t stream) {
  const float* x = (const float*)d_in[0];
  const float* Wq = (const float*)d_in[1];
  const float* Wk = (const float*)d_in[2];
  const float* Wv = (const float*)d_in[3];
  const float* Wo = (const float*)d_in[4];
  const float* gamma = (const float*)d_in[5];
  const float* beta = (const float*)d_in[6];
  float* out = (float*)d_out;

  char* ws = (char*)d_ws;
  const size_t MB = 1024ull * 1024ull;
  bf16* Xb = (bf16*)(ws + 0);             // 16 MB [8192,1024]
  bf16* Wcat = (bf16*)(ws + 16 * MB);     // 6 MB  [3072,1024]
  bf16* Wot = (bf16*)(ws + 22 * MB);      // 2 MB  [1024,1024]
  bf16* Qd = (bf16*)(ws + 24 * MB);       // 16 MB [8192,1024]
  bf16* Kd = (bf16*)(ws + 40 * MB);       // 16 MB [8192,1024]
  bf16* Vd = (bf16*)(ws + 56 * MB);       // 16 MB [8192,1024]
  bf16* expS = (bf16*)(ws + 72 * MB);     // 32 MB [4][2048,2048]
  float* lsum = (float*)(ws + 104 * MB);  // 32 KB [4][2048]
  bf16* VWo = (bf16*)(ws + 105 * MB);     // 16 MB [4][1024,2048] (d, s)
  bf16* Hd = (bf16*)(ws + 121 * MB);      // 16 MB [8192,1024]

  static int inited = 0;
  if (!inited) {
    hipFuncSetAttribute(reinterpret_cast<const void*>(&gemm256<1>),
                        hipFuncAttributeMaxDynamicSharedMemorySize, 131072);
    inited = 1;
  }

  prep<<<8192, 256, 0, stream>>>(x, Wq, Wk, Wv, Wo, Xb, Wcat, Wot, lsum);

  // Q/K/V = Xb @ Wcat^T (M=8192,N=3072,K=1024): 1536 blocks = perfect rounds
  gemm128<4><<<dim3(24, 64, 1), 256, 32768, stream>>>(
      Xb, Wcat, Qd, 1024, 1024, 1024, 1024, 0, 0, 0, 1.f, nullptr, Kd, Vd);

  // expS = exp(Q @ K^T / 32), lsum = row sums (M=N=2048,K=1024, x4):
  // 256 blocks = exactly 1 round of gemm256
  gemm256<1><<<dim3(8, 8, 4), 512, 131072, stream>>>(
      Qd, Kd, expS, 1024, 1024, 1024, 2048, 2048 * 1024LL, 2048 * 1024LL,
      2048 * 2048LL, 0.03125f, lsum, nullptr, nullptr);

  // VWo[d][s] = Wot @ V^T  (A=Wot [1024,1024], B=V [2048,1024], x4): 512 blocks
  gemm128<0><<<dim3(16, 8, 4), 256, 32768, stream>>>(
      Wot, Vd, VWo, 1024, 1024, 1024, 2048, 0, 2048 * 1024LL, 1024 * 2048LL,
      1.f, nullptr, nullptr, nullptr);

  // hidden = (expS @ VWo^T) / lsum  (M=2048,N=1024,K=2048, x4): 512 blocks
  gemm128<2><<<dim3(8, 16, 4), 256, 32768, stream>>>(
      expS, VWo, Hd, 2048, 2048, 2048, 1024, 2048 * 2048LL, 1024 * 2048LL,
      2048 * 1024LL, 1.f, lsum, nullptr, nullptr);

  layernorm_rows<<<8192, 256, 0, stream>>>(Hd, gamma, beta, out);
}